// Round 3
// baseline (129.374 us; speedup 1.0000x reference)
//
#include <hip/hip_runtime.h>

// B=64, K=8, H=W=128 (HW=16384). float32 in/out.
// out[0] = loss scalar; out[1..] = pred_perm (B,K,H,W) flat.
//
// 2-dispatch pipeline:
//   cost_kernel    : 256 blocks (1 per CU, LDS-forced). ROW-SEQUENTIAL BURST
//                    staging: per 4KB x-window, each wave owns 4 rows and issues
//                    each row's full 4KB as 4 contiguous global_load_lds before
//                    hopping rows. DRAM sees sequential 4KB runs instead of the
//                    16-way interleaved 1KB-chunk 64KB-strided streams that both
//                    prior structures (LDS-staged 38us, reg-stream ~34us) shared
//                    -- testing the channel-alias theory of the ~1.9 TB/s cap.
//                    Double-buffered (128KB LDS), STAGE-after-barrier overlap;
//                    acc[64]/thread; verified reduce-scatter epilogue.
//   permute_kernel : 512 blocks (full row each): fused Held-Karp DP (redundant per
//                    block, parallel) + permuted copy with aligned float4 stores;
//                    one block per batch atomicAdds the batch loss into out[0].

#define BB 64
#define KK 8
#define HW 16384
#define SPANS 4      // cost blocks per batch
#define SPAN 4096    // floats per span per row
#define WIN 1024     // floats per window per row (4KB bursts)
#define NWIN 4       // windows per span
#define EPSF 1e-15f

// ---------- compile-time mask table: all 255 nonzero 8-bit masks, level-ordered by popcount ----------
struct MaskTab {
    unsigned char masks[255];
    int off[9];
};

constexpr MaskTab make_tab() {
    MaskTab t{};
    int idx = 0;
    for (int p = 1; p <= 8; ++p) {
        t.off[p - 1] = idx;
        for (int m = 1; m < 256; ++m) {
            int c = 0;
            for (int b = 0; b < 8; ++b) c += (m >> b) & 1;
            if (c == p) t.masks[idx++] = (unsigned char)m;
        }
    }
    t.off[8] = idx;
    return t;
}

__constant__ MaskTab kTab = make_tab();

__device__ __forceinline__ float dot4(float4 t, float4 l) {
    return t.x * l.x + t.y * l.y + t.z * l.z + t.w * l.w;
}

__device__ __forceinline__ float4 log4(float4 a) {
    float4 r;
    r.x = __logf(a.x + EPSF); r.y = __logf(a.y + EPSF);
    r.z = __logf(a.z + EPSF); r.w = __logf(a.w + EPSF);
    return r;
}

// ---------- phase 1: row-sequential-burst LDS staging + register accumulators ----------
// Grid: 256 blocks (b*4+s), 256 threads, 129KB LDS -> exactly 1 block/CU.
// Per window (4KB/row): wave w stages rows 4w..4w+3, each row as 4 back-to-back
// 1KB global_load_lds (a contiguous 4KB burst per row). Compute: thread t owns
// x-quad t of the window, accumulates all 64 cross dots + 8 ent dots.
__global__ __launch_bounds__(256) void cost_kernel(const float* __restrict__ pred,
                                                   const float* __restrict__ aug,
                                                   float* __restrict__ part,   // [256][72]
                                                   float* __restrict__ out)
{
    __shared__ float tile[2][16][WIN];
    __shared__ float red[4][72];

    const int blk  = blockIdx.x;        // b*SPANS + s
    const int b    = blk >> 2;
    const int s    = blk & 3;
    const int tid  = threadIdx.x;
    const int wave = tid >> 6;
    const int lane = tid & 63;

    if (blk == 0 && tid == 0) out[0] = 0.f;   // loss accumulator init (pre-atomics)

    const size_t base = (size_t)b * (KK * HW) + (size_t)s * SPAN;
    const int e4 = lane * 4;            // float offset of this lane's 16B within a 1KB chunk

    // STAGE(w): row-sequential. Wave `wave` issues rows 4*wave+k (k=0..3); for each
    // row, 4 contiguous 1KB chunks back-to-back => 4KB sequential per row.
#define STAGE(w)                                                                          \
    {                                                                                     \
        const int pb_ = (w) & 1;                                                          \
        _Pragma("unroll")                                                                 \
        for (int k = 0; k < 4; ++k) {                                                     \
            const int vr = 4 * wave + k;                                                  \
            const float* rp = ((vr < 8) ? (pred + base + (size_t)vr * HW)                 \
                                        : (aug + base + (size_t)(vr - 8) * HW))           \
                              + (w) * WIN;                                                \
            _Pragma("unroll")                                                             \
            for (int c = 0; c < 4; ++c) {                                                 \
                __builtin_amdgcn_global_load_lds(                                         \
                    (const __attribute__((address_space(1))) void*)(rp + c * 256 + e4),   \
                    (__attribute__((address_space(3))) void*)&tile[pb_][vr][c * 256 + e4],\
                    16, 0, 0);                                                            \
            }                                                                             \
        }                                                                                 \
    }

    float acc[64];
#pragma unroll
    for (int v = 0; v < 64; ++v) acc[v] = 0.f;
    float ent[8];
#pragma unroll
    for (int j = 0; j < 8; ++j) ent[j] = 0.f;

    STAGE(0)

#pragma unroll
    for (int w = 0; w < NWIN; ++w) {
        __syncthreads();                 // drains vmcnt: STAGE(w) landed
        if (w + 1 < NWIN) STAGE(w + 1)   // async into other buffer, overlaps compute

        const int pb = w & 1;
        const int q4 = tid * 4;          // this thread's x-quad within the window

        float4 lp[8];
#pragma unroll
        for (int i = 0; i < 8; ++i)
            lp[i] = log4(*(const float4*)&tile[pb][i][q4]);

#pragma unroll
        for (int j = 0; j < 8; ++j) {
            const float4 a = *(const float4*)&tile[pb][8 + j][q4];
            ent[j] += dot4(a, log4(a));
#pragma unroll
            for (int i = 0; i < 8; ++i)
                acc[i * 8 + j] += dot4(a, lp[i]);
        }
    }
#undef STAGE

    // --- wave reduce-scatter over the 64 cross accumulators (63 shuffles) ---
    // After round r (d=1<<r), live count halves; lane l ends with the wave-total
    // of original acc[bitrev6(l)].
#pragma unroll
    for (int r = 0; r < 6; ++r) {
        const int d    = 1 << r;
        const int half = 32 >> r;
        const bool hi  = (lane & d) != 0;
#pragma unroll
        for (int k = 0; k < half; ++k) {
            const float send = hi ? acc[k] : acc[k + half];
            const float recv = __shfl_xor(send, d);
            acc[k] = (hi ? acc[k + half] : acc[k]) + recv;
        }
    }

    // --- ent reduce: 3-round reduce-scatter over 8 values + 3 plain butterflies ---
#pragma unroll
    for (int r = 0; r < 3; ++r) {
        const int d    = 1 << r;
        const int half = 4 >> r;
        const bool hi  = (lane & d) != 0;
#pragma unroll
        for (int k = 0; k < half; ++k) {
            const float send = hi ? ent[k] : ent[k + half];
            const float recv = __shfl_xor(send, d);
            ent[k] = (hi ? ent[k + half] : ent[k]) + recv;
        }
    }
    float ev = ent[0];
    ev += __shfl_xor(ev, 8);
    ev += __shfl_xor(ev, 16);
    ev += __shfl_xor(ev, 32);
    // lane l holds ent_total[bitrev3(l & 7)]

    // --- combine the 4 waves via LDS, store 72 partials ---
    const int vidx = ((lane & 1) << 5) | ((lane & 2) << 3) | ((lane & 4) << 1) |
                     ((lane & 8) >> 1) | ((lane & 16) >> 3) | ((lane & 32) >> 5);
    red[wave][vidx] = acc[0];
    if (lane < 8)
        red[wave][64 + (((lane & 1) << 2) | (lane & 2) | ((lane & 4) >> 2))] = ev;
    __syncthreads();

    if (tid < 72) {
        const float ssum = red[0][tid] + red[1][tid] + red[2][tid] + red[3][tid];
        part[(size_t)blk * 72 + tid] = ssum;   // part[i*8+j]=cross[i][j]; part[64+j]=ent[j]
    }
}

// ---------- phase 2: fused DP + permuted copy (512 blocks, full row each) ----------
// grid: 512 blocks of 256 threads; block p handles pair p = b*8 + jcol (one full
// 16384-float row). Each block redundantly reduces its batch's 4 span-partials and
// runs the Held-Karp DP (~parallel). Block p==b*8 atomicAdds the batch loss.
// Stores: out+1 row base is 4B-aligned; element 3 of each row is 16B-aligned ->
// middle 4095 quads as aligned float4; head 3 + tail 1 scalar by one thread.
__global__ __launch_bounds__(256) void permute_kernel(const float* __restrict__ pred,
                                                      const float* __restrict__ part,
                                                      float* __restrict__ out)
{
    __shared__ float red[72];
    __shared__ float C[64];     // C[i*8+j] = ent[j] - cross[i][j] (unscaled)
    __shared__ float dp[256];
    __shared__ int   choice[256];
    __shared__ int   inv8[8];   // col -> src row

    const int p    = blockIdx.x;   // pair = b*8 + jcol
    const int b    = p >> 3;
    const int tid  = threadIdx.x;

    // --- reduce the 4 span-partials for batch b ---
    const float* pb = part + (size_t)b * SPANS * 72;
    if (tid < 72) {
        float s = 0.f;
#pragma unroll
        for (int c = 0; c < SPANS; ++c) s += pb[c * 72 + tid];
        red[tid] = s;
    }
    if (tid == 0) dp[0] = 0.f;
    __syncthreads();
    if (tid < 64) C[tid] = red[64 + (tid & 7)] - red[tid];
    __syncthreads();

    // --- Held-Karp DP over 255 masks, level-ordered; 32 mask slots per pass ---
    const int grp = tid >> 3;
    const int j   = tid & 7;
    for (int lvl = 1; lvl <= 8; ++lvl) {
        const int start = kTab.off[lvl - 1];
        const int end   = kTab.off[lvl];
        const float* Crow = &C[(lvl - 1) * 8];
        for (int bse = start; bse < end; bse += 32) {
            const int mi = bse + grp;
            if (mi < end) {
                const int M = kTab.masks[mi];
                float v  = 1e30f;
                int   bj = 0;
                if (M & (1 << j)) {
                    v  = dp[M ^ (1 << j)] + Crow[j];
                    bj = j;
                }
#pragma unroll
                for (int d = 1; d < 8; d <<= 1) {
                    const float ov = __shfl_xor(v, d);
                    const int   oj = __shfl_xor(bj, d);
                    if (ov < v) { v = ov; bj = oj; }
                }
                if (j == 0) { dp[M] = v; choice[M] = bj; }
            }
        }
        __syncthreads();
    }

    if (tid == 0) {
        int mask = 255;
        for (int r = 7; r >= 0; --r) {
            const int jj = choice[mask];
            inv8[jj] = r;              // column jj takes pred row r
            mask ^= 1 << jj;
        }
        if ((p & 7) == 0)              // one designated block per batch
            atomicAdd(out, dp[255] * (1.0f / (16384.0f * 512.0f)));
    }
    __syncthreads();

    // --- permuted copy of the full row (16384 elements = 4096 quads) ---
    const int src_row = inv8[p & 7];   // uniform per block
    const float* src  = pred + ((size_t)(b << 3) + src_row) * HW;
    float*      drow  = out + 1 + (size_t)p * HW;

#pragma unroll
    for (int m = 0; m < 16; ++m) {
        const int f = tid + 256 * m;              // quad index in [0,4096)
        const int e = 3 + 4 * f;
        if (f < 4095) {
            float4 v;
            v.x = src[e]; v.y = src[e + 1]; v.z = src[e + 2]; v.w = src[e + 3];
            *(float4*)(drow + e) = v;             // 16B-aligned
        } else {                                  // f==4095: head 3 + tail 1
            drow[0] = src[0]; drow[1] = src[1]; drow[2] = src[2];
            drow[16383] = src[16383];
        }
    }
}

extern "C" void kernel_launch(void* const* d_in, const int* in_sizes, int n_in,
                              void* d_out, int out_size, void* d_ws, size_t ws_size,
                              hipStream_t stream) {
    const float* pred = (const float*)d_in[0];
    const float* aug  = (const float*)d_in[1];
    float* out = (float*)d_out;
    float* part = (float*)d_ws;                      // 256*72 floats

    cost_kernel<<<dim3(BB * SPANS), dim3(256), 0, stream>>>(pred, aug, part, out);
    permute_kernel<<<dim3(512), dim3(256), 0, stream>>>(pred, part, out);
}

// Round 4
// 120.645 us; speedup vs baseline: 1.0724x; 1.0724x over previous
//
#include <hip/hip_runtime.h>

// B=64, K=8, H=W=128 (HW=16384). float32 in/out.
// out[0] = loss scalar; out[1..] = pred_perm (B,K,H,W) flat.
//
// 2-dispatch pipeline:
//   cost_kernel    : 1024 blocks, ONE x-quad per thread. Loads all 16 float4s
//                    (8 pred + 8 aug rows) into registers BEFORE any compute --
//                    acc[] is not live during the load phase, so the scheduler
//                    clusters all 16 global_load_dwordx4 (16KB/wave in flight;
//                    sched_barrier(0) pins it). Theory: r0/r2/r3 all capped at
//                    ~2 TB/s because loads were issue-serialized (reg pressure
//                    sank them to first use) or barrier-drained; this variant
//                    maximizes memory-level parallelism with zero barriers.
//                    Epilogue: verified 63-shuffle reduce-scatter + LDS combine.
//   permute_kernel : 512 blocks (full row each): fused Held-Karp DP (redundant per
//                    block, parallel) + permuted copy with aligned float4 stores;
//                    one block per batch atomicAdds the batch loss into out[0].

#define BB 64
#define KK 8
#define HW 16384
#define SPANS 16     // cost blocks per batch
#define SPAN 1024    // floats per span per row (one quad per thread)
#define EPSF 1e-15f

// ---------- compile-time mask table: all 255 nonzero 8-bit masks, level-ordered by popcount ----------
struct MaskTab {
    unsigned char masks[255];
    int off[9];
};

constexpr MaskTab make_tab() {
    MaskTab t{};
    int idx = 0;
    for (int p = 1; p <= 8; ++p) {
        t.off[p - 1] = idx;
        for (int m = 1; m < 256; ++m) {
            int c = 0;
            for (int b = 0; b < 8; ++b) c += (m >> b) & 1;
            if (c == p) t.masks[idx++] = (unsigned char)m;
        }
    }
    t.off[8] = idx;
    return t;
}

__constant__ MaskTab kTab = make_tab();

__device__ __forceinline__ float dot4(float4 t, float4 l) {
    return t.x * l.x + t.y * l.y + t.z * l.z + t.w * l.w;
}

__device__ __forceinline__ float4 log4(float4 a) {
    float4 r;
    r.x = __logf(a.x + EPSF); r.y = __logf(a.y + EPSF);
    r.z = __logf(a.z + EPSF); r.w = __logf(a.w + EPSF);
    return r;
}

// ---------- phase 1: max-MLP register streaming, one quad per thread ----------
// Grid: 1024 blocks (b*16+s), 256 threads. Thread t of span s owns x-quad
// s*256+t of every row. All 16 loads issue before any compute (no acc live).
__global__ __launch_bounds__(256) void cost_kernel(const float* __restrict__ pred,
                                                   const float* __restrict__ aug,
                                                   float* __restrict__ part,   // [1024][72]
                                                   float* __restrict__ out)
{
    __shared__ float red[4][72];

    const int blk  = blockIdx.x;        // b*SPANS + s
    const int b    = blk >> 4;
    const int s    = blk & 15;
    const int tid  = threadIdx.x;
    const int wave = tid >> 6;
    const int lane = tid & 63;

    if (blk == 0 && tid == 0) out[0] = 0.f;   // loss accumulator init (pre-atomics)

    const size_t base = (size_t)b * (KK * HW) + (size_t)s * SPAN + (size_t)tid * 4;
    const float* pp = pred + base;
    const float* ap = aug  + base;

    // --- load phase: 16 independent global_load_dwordx4, nothing else live ---
    float4 pv[8], av[8];
#pragma unroll
    for (int i = 0; i < 8; ++i) pv[i] = *(const float4*)(pp + (size_t)i * HW);
#pragma unroll
    for (int j = 0; j < 8; ++j) av[j] = *(const float4*)(ap + (size_t)j * HW);
    __builtin_amdgcn_sched_barrier(0);   // pin: all loads issued before compute

    // --- compute phase: logs once, 64 cross dots + 8 ent dots, single-assign ---
    float4 lp[8];
#pragma unroll
    for (int i = 0; i < 8; ++i) lp[i] = log4(pv[i]);

    float acc[64];
    float ent[8];
#pragma unroll
    for (int j = 0; j < 8; ++j) {
        const float4 a = av[j];
        ent[j] = dot4(a, log4(a));
#pragma unroll
        for (int i = 0; i < 8; ++i)
            acc[i * 8 + j] = dot4(a, lp[i]);
    }

    // --- wave reduce-scatter over the 64 cross accumulators (63 shuffles) ---
    // After round r (d=1<<r), live count halves; lane l ends with the wave-total
    // of original acc[bitrev6(l)].
#pragma unroll
    for (int r = 0; r < 6; ++r) {
        const int d    = 1 << r;
        const int half = 32 >> r;
        const bool hi  = (lane & d) != 0;
#pragma unroll
        for (int k = 0; k < half; ++k) {
            const float send = hi ? acc[k] : acc[k + half];
            const float recv = __shfl_xor(send, d);
            acc[k] = (hi ? acc[k + half] : acc[k]) + recv;
        }
    }

    // --- ent reduce: 3-round reduce-scatter over 8 values + 3 plain butterflies ---
#pragma unroll
    for (int r = 0; r < 3; ++r) {
        const int d    = 1 << r;
        const int half = 4 >> r;
        const bool hi  = (lane & d) != 0;
#pragma unroll
        for (int k = 0; k < half; ++k) {
            const float send = hi ? ent[k] : ent[k + half];
            const float recv = __shfl_xor(send, d);
            ent[k] = (hi ? ent[k + half] : ent[k]) + recv;
        }
    }
    float ev = ent[0];
    ev += __shfl_xor(ev, 8);
    ev += __shfl_xor(ev, 16);
    ev += __shfl_xor(ev, 32);
    // lane l holds ent_total[bitrev3(l & 7)]

    // --- combine the 4 waves via LDS, store 72 partials ---
    const int vidx = ((lane & 1) << 5) | ((lane & 2) << 3) | ((lane & 4) << 1) |
                     ((lane & 8) >> 1) | ((lane & 16) >> 3) | ((lane & 32) >> 5);
    red[wave][vidx] = acc[0];
    if (lane < 8)
        red[wave][64 + (((lane & 1) << 2) | (lane & 2) | ((lane & 4) >> 2))] = ev;
    __syncthreads();

    if (tid < 72) {
        const float ssum = red[0][tid] + red[1][tid] + red[2][tid] + red[3][tid];
        part[(size_t)blk * 72 + tid] = ssum;   // part[i*8+j]=cross[i][j]; part[64+j]=ent[j]
    }
}

// ---------- phase 2: fused DP + permuted copy (512 blocks, full row each) ----------
// grid: 512 blocks of 256 threads; block p handles pair p = b*8 + jcol (one full
// 16384-float row). Each block redundantly reduces its batch's 16 span-partials and
// runs the Held-Karp DP (~parallel). Block p==b*8 atomicAdds the batch loss.
// Stores: out+1 row base is 4B-aligned; element 3 of each row is 16B-aligned ->
// middle 4095 quads as aligned float4; head 3 + tail 1 scalar by one thread.
__global__ __launch_bounds__(256) void permute_kernel(const float* __restrict__ pred,
                                                      const float* __restrict__ part,
                                                      float* __restrict__ out)
{
    __shared__ float red[72];
    __shared__ float C[64];     // C[i*8+j] = ent[j] - cross[i][j] (unscaled)
    __shared__ float dp[256];
    __shared__ int   choice[256];
    __shared__ int   inv8[8];   // col -> src row

    const int p    = blockIdx.x;   // pair = b*8 + jcol
    const int b    = p >> 3;
    const int tid  = threadIdx.x;

    // --- reduce the 16 span-partials for batch b ---
    const float* pb = part + (size_t)b * SPANS * 72;
    if (tid < 72) {
        float s = 0.f;
#pragma unroll
        for (int c = 0; c < SPANS; ++c) s += pb[c * 72 + tid];
        red[tid] = s;
    }
    if (tid == 0) dp[0] = 0.f;
    __syncthreads();
    if (tid < 64) C[tid] = red[64 + (tid & 7)] - red[tid];
    __syncthreads();

    // --- Held-Karp DP over 255 masks, level-ordered; 32 mask slots per pass ---
    const int grp = tid >> 3;
    const int j   = tid & 7;
    for (int lvl = 1; lvl <= 8; ++lvl) {
        const int start = kTab.off[lvl - 1];
        const int end   = kTab.off[lvl];
        const float* Crow = &C[(lvl - 1) * 8];
        for (int bse = start; bse < end; bse += 32) {
            const int mi = bse + grp;
            if (mi < end) {
                const int M = kTab.masks[mi];
                float v  = 1e30f;
                int   bj = 0;
                if (M & (1 << j)) {
                    v  = dp[M ^ (1 << j)] + Crow[j];
                    bj = j;
                }
#pragma unroll
                for (int d = 1; d < 8; d <<= 1) {
                    const float ov = __shfl_xor(v, d);
                    const int   oj = __shfl_xor(bj, d);
                    if (ov < v) { v = ov; bj = oj; }
                }
                if (j == 0) { dp[M] = v; choice[M] = bj; }
            }
        }
        __syncthreads();
    }

    if (tid == 0) {
        int mask = 255;
        for (int r = 7; r >= 0; --r) {
            const int jj = choice[mask];
            inv8[jj] = r;              // column jj takes pred row r
            mask ^= 1 << jj;
        }
        if ((p & 7) == 0)              // one designated block per batch
            atomicAdd(out, dp[255] * (1.0f / (16384.0f * 512.0f)));
    }
    __syncthreads();

    // --- permuted copy of the full row (16384 elements = 4096 quads) ---
    const int src_row = inv8[p & 7];   // uniform per block
    const float* src  = pred + ((size_t)(b << 3) + src_row) * HW;
    float*      drow  = out + 1 + (size_t)p * HW;

#pragma unroll
    for (int m = 0; m < 16; ++m) {
        const int f = tid + 256 * m;              // quad index in [0,4096)
        const int e = 3 + 4 * f;
        if (f < 4095) {
            float4 v;
            v.x = src[e]; v.y = src[e + 1]; v.z = src[e + 2]; v.w = src[e + 3];
            *(float4*)(drow + e) = v;             // 16B-aligned
        } else {                                  // f==4095: head 3 + tail 1
            drow[0] = src[0]; drow[1] = src[1]; drow[2] = src[2];
            drow[16383] = src[16383];
        }
    }
}

extern "C" void kernel_launch(void* const* d_in, const int* in_sizes, int n_in,
                              void* d_out, int out_size, void* d_ws, size_t ws_size,
                              hipStream_t stream) {
    const float* pred = (const float*)d_in[0];
    const float* aug  = (const float*)d_in[1];
    float* out = (float*)d_out;
    float* part = (float*)d_ws;                      // 1024*72 floats

    cost_kernel<<<dim3(BB * SPANS), dim3(256), 0, stream>>>(pred, aug, part, out);
    permute_kernel<<<dim3(512), dim3(256), 0, stream>>>(pred, part, out);
}